// Round 5
// baseline (193.176 us; speedup 1.0000x reference)
//
#include <hip/hip_runtime.h>

#define BB 2
#define NN 256
#define MM 512
#define INF_ 256
#define OUTF 128
#define NBLK 512

// Agent-scope global barrier: monotonic counter per phase (zeroed each launch
// by a hipMemsetAsync node). Release fence -> add; spin; acquire fence.
// __threadfence() at agent scope emits the L2 writeback/invalidate needed for
// cross-XCD visibility (same mechanism cg uses; proven correct in round 3).
__device__ __forceinline__ void gbar(int* cnt, int idx) {
    __syncthreads();
    if (threadIdx.x == 0) {
        __threadfence();
        __hip_atomic_fetch_add(&cnt[idx], 1, __ATOMIC_RELEASE,
                               __HIP_MEMORY_SCOPE_AGENT);
        while (__hip_atomic_load(&cnt[idx], __ATOMIC_ACQUIRE,
                                 __HIP_MEMORY_SCOPE_AGENT) < NBLK) {
            __builtin_amdgcn_s_sleep(2);
        }
        __threadfence();
    }
    __syncthreads();
}

union SM {
    struct { float xs[INF_]; float accs[256]; float r0[4], r1[4]; } p1;
    struct { float sh0[NN], sh1[NN], sd[256], ss0[256], ss1[256]; } p2;
    struct { float sem0[MM], sem1[MM]; } p3;
    struct { float sW[NN], sA0[NN], sA1[NN]; float2 sacc[2][128]; } p4;
};

__global__ __launch_bounds__(256) void k_fused(
        const float* __restrict__ X, const float* __restrict__ A,
        const float* __restrict__ W, const float* __restrict__ avec,
        float* __restrict__ H, float* __restrict__ h0,
        float* __restrict__ h1, float* __restrict__ cH,
        float* __restrict__ em0, float* __restrict__ em1,
        float* __restrict__ rs0, float* __restrict__ rs1,
        int* cnt, float* __restrict__ out) {
    __shared__ SM sm;
    const int blk = blockIdx.x;
    const int t = threadIdx.x;
    const int lane = t & 63, wv = t >> 6;

    // ---------------- P1: H = X@W ; h0 = H.a0, h1 = H.a1, cH = leaky(h0+h1)
    {
        const int bn = blk;                 // 0..511
        const int f = t & 127, kh = t >> 7;
        sm.p1.xs[t] = X[bn * INF_ + t];
        __syncthreads();
        float acc = 0.f;
        const float* Wp = W + kh * 128 * OUTF + f;
        const float* xp = sm.p1.xs + kh * 128;
#pragma unroll 8
        for (int k = 0; k < 128; ++k) acc += xp[k] * Wp[k * OUTF];
        sm.p1.accs[t] = acc;
        __syncthreads();
        float a2 = 0.f, p0 = 0.f, p1 = 0.f;
        if (t < 128) {
            a2 = sm.p1.accs[t] + sm.p1.accs[t + 128];
            H[bn * OUTF + t] = a2;
            p0 = a2 * avec[t];
            p1 = a2 * avec[OUTF + t];
        }
#pragma unroll
        for (int off = 32; off >= 1; off >>= 1) {
            p0 += __shfl_down(p0, off);
            p1 += __shfl_down(p1, off);
        }
        if (lane == 0) { sm.p1.r0[wv] = p0; sm.p1.r1[wv] = p1; }
        __syncthreads();
        if (t == 0) {
            float s0 = sm.p1.r0[0] + sm.p1.r0[1] + sm.p1.r0[2] + sm.p1.r0[3];
            float s1 = sm.p1.r1[0] + sm.p1.r1[1] + sm.p1.r1[2] + sm.p1.r1[3];
            h0[bn] = s0;
            h1[bn] = s1;
            float hA = s0 + s1;
            cH[bn] = hA > 0.f ? hA : 0.01f * hA;   // leaky_relu 0.01
        }
    }
    gbar(cnt, 0);

    // ---------------- P2 (blocks 0..31): em0/em1 = (A^T h)/deg
    if (blk < 32) {
        const int b = blk >> 4, mq = blk & 15;
        const int m_l = t & 31, n_l = t >> 5;
        sm.p2.sh0[t] = h0[b * NN + t];
        sm.p2.sh1[t] = h1[b * NN + t];
        __syncthreads();
        const float* Ap = A + (size_t)b * NN * MM + mq * 32 + m_l;
        float d = 0.f, s0 = 0.f, s1 = 0.f;
#pragma unroll 8
        for (int i = 0; i < 32; ++i) {
            int n = n_l * 32 + i;
            float av = Ap[n * MM];          // coalesced across m_l
            d += av;
            s0 += av * sm.p2.sh0[n];
            s1 += av * sm.p2.sh1[n];
        }
        sm.p2.sd[t] = d; sm.p2.ss0[t] = s0; sm.p2.ss1[t] = s1;
        __syncthreads();
        if (t < 32) {
            float D = 0.f, S0 = 0.f, S1 = 0.f;
#pragma unroll
            for (int j = 0; j < 8; ++j) {
                D  += sm.p2.sd[j * 32 + t];
                S0 += sm.p2.ss0[j * 32 + t];
                S1 += sm.p2.ss1[j * 32 + t];
            }
            if (D == 0.f) D = 1.f;
            em0[b * MM + mq * 32 + t] = S0 / D;
            em1[b * MM + mq * 32 + t] = S1 / D;
        }
    }
    gbar(cnt, 1);

    // ---------------- P3 (blocks 0..127): per-row softmax stats, 4 rows/block
    if (blk < 128) {
        const int bn = blk * 4 + wv;
        const int b = bn >> 8, n = bn & 255;
        const bool low = ((blk * 4) & 255) < 128;   // uniform per block
        if (!low) {
            sm.p3.sem0[t] = em0[b * MM + t];
            sm.p3.sem0[t + 256] = em0[b * MM + t + 256];
            sm.p3.sem1[t] = em1[b * MM + t];
            sm.p3.sem1[t + 256] = em1[b * MM + t + 256];
        }
        __syncthreads();
        const float* Ar = A + (size_t)bn * MM;
        if (low) {
            float c0 = 0.f, c1 = 0.f;
#pragma unroll
            for (int i = 0; i < 8; ++i) {
                float av = Ar[lane + 64 * i];
                if (i < 4) c0 += av; else c1 += av;
            }
#pragma unroll
            for (int off = 32; off >= 1; off >>= 1) {
                c0 += __shfl_xor(c0, off);
                c1 += __shfl_xor(c1, off);
            }
            if (lane == 0) {
                float ch0 = cH[b * NN + 2 * n];
                float ch1 = cH[b * NN + 2 * n + 1];
                float mx = fmaxf(c0 > 0.f ? ch0 : -INFINITY,
                                 c1 > 0.f ? ch1 : -INFINITY);
                float e0 = c0 > 0.f ? expf(ch0 - mx) : 0.f;
                float e1 = c1 > 0.f ? expf(ch1 - mx) : 0.f;
                float inv = 1.f / (c0 * e0 + c1 * e1);
                rs0[bn] = e0 * inv;
                rs1[bn] = e1 * inv;
            }
        } else {
            float av[8], eL[8];
#pragma unroll
            for (int i = 0; i < 8; ++i) {
                int m = lane + 64 * i;
                av[i] = Ar[m];
                float v = sm.p3.sem0[(2 * m) & (MM - 1)] +
                          sm.p3.sem1[(2 * m + 1) & (MM - 1)];
                eL[i] = v > 0.f ? v : 0.01f * v;
            }
            float mx = -INFINITY;
#pragma unroll
            for (int i = 0; i < 8; ++i) if (av[i] > 0.f) mx = fmaxf(mx, eL[i]);
#pragma unroll
            for (int off = 32; off >= 1; off >>= 1)
                mx = fmaxf(mx, __shfl_xor(mx, off));
            float s = 0.f;
#pragma unroll
            for (int i = 0; i < 8; ++i)
                if (av[i] > 0.f) s += expf(eL[i] - mx);
#pragma unroll
            for (int off = 32; off >= 1; off >>= 1) s += __shfl_xor(s, off);
            if (lane == 0) {
                rs0[bn] = expf(-mx) / s;
                rs1[bn] = 0.f;
            }
        }
    }
    gbar(cnt, 2);

    // ---------------- P4: out[b,m,f] = sum_n att(b,n,m) * H[b,n,f]
    // block = (b, m-pair mp); 256 thr = (mh = t>>7, nh = (t>>6)&1, f2 = t&63)
    // high-n factor e^{eLow[m]} pulled out of the loop: out = lo + eE*hi.
    {
        const int b = blk >> 8, mp = blk & 255;
        const int m0 = 2 * mp, m1 = 2 * mp + 1;
        const float* rsSel = (mp < 128) ? rs0 : rs1;   // w-half for low rows
        sm.p4.sW[t] = (t < 128) ? rsSel[b * NN + t] : rs0[b * NN + t];
        sm.p4.sA0[t] = A[((size_t)(b * NN + t)) * MM + m0];
        sm.p4.sA1[t] = A[((size_t)(b * NN + t)) * MM + m1];
        __syncthreads();
        const int f2 = t & 63;
        const int nh = (t >> 6) & 1;
        const int mh = t >> 7;
        const float* sA = mh ? sm.p4.sA1 : sm.p4.sA0;
        const float2* H2 = (const float2*)H + (size_t)b * NN * 64 + f2;
        float2 acc = {0.f, 0.f};
#pragma unroll 8
        for (int i = 0; i < 128; ++i) {
            int n = nh * 128 + i;
            float c = sA[n] * sm.p4.sW[n];      // LDS broadcasts
            float2 hv = H2[n * 64];             // coalesced 8B/lane
            acc.x = fmaf(c, hv.x, acc.x);
            acc.y = fmaf(c, hv.y, acc.y);
        }
        sm.p4.sacc[nh][mh * 64 + f2] = acc;
        __syncthreads();
        if (t < 128) {
            int mh2 = t >> 6, f2b = t & 63;
            int m = mp * 2 + mh2;
            float v = em0[b * MM + ((2 * m) & (MM - 1))] +
                      em1[b * MM + ((2 * m + 1) & (MM - 1))];
            v = v > 0.f ? v : 0.01f * v;
            float eE = expf(v);                 // e^{eLow[m]}
            float2 lo = sm.p4.sacc[0][t];
            float2 hi = sm.p4.sacc[1][t];
            float2 r;
            r.x = lo.x + eE * hi.x;
            r.y = lo.y + eE * hi.y;
            ((float2*)out)[((size_t)b * MM + m) * 64 + f2b] = r;
        }
    }
}

extern "C" void kernel_launch(void* const* d_in, const int* in_sizes, int n_in,
                              void* d_out, int out_size, void* d_ws, size_t ws_size,
                              hipStream_t stream) {
    const float* X = (const float*)d_in[0];
    const float* A = (const float*)d_in[1];
    const float* W = (const float*)d_in[2];
    const float* a = (const float*)d_in[3];
    float* out = (float*)d_out;
    float* ws = (float*)d_ws;

    float* H   = ws;            // B*N*OUTF = 65536
    float* h0  = ws + 65536;    // 512
    float* h1  = ws + 66048;    // 512
    float* cH  = ws + 66560;    // 512
    float* em0 = ws + 67072;    // B*M = 1024
    float* em1 = ws + 68096;    // B*M = 1024
    float* rs0 = ws + 69120;    // B*N = 512
    float* rs1 = ws + 69632;    // B*N = 512
    int* cnt   = (int*)(ws + 71680);   // 3 barrier counters

    hipMemsetAsync(cnt, 0, 3 * sizeof(int), stream);
    k_fused<<<NBLK, 256, 0, stream>>>(X, A, W, a, H, h0, h1, cH,
                                      em0, em1, rs0, rs1, cnt, out);
}

// Round 6
// 32.497 us; speedup vs baseline: 5.9444x; 5.9444x over previous
//
#include <hip/hip_runtime.h>

#define BB 2
#define NN 256
#define MM 512
#define INF_ 256
#define OUTF 128

// K1 "head": 32 blocks (b = blk>>4, mq = blk&15), 256 thr.
// Per block (redundantly where needed, cheap):
//   wa0/wa1 = W @ a-halves; h0/h1[n] = X[b,n,:]·wa (all 256 rows of b);
//   cH = leaky(h0+h1) (written by mq==0 blocks);
//   em0/em1 for the block's 32 owned columns; g[m] = exp(leaky(em0[2m%M]+em1[(2m+1)%M]))
//   for the block's 16 owned g-slots (duplicated at m and m+256).
__global__ __launch_bounds__(256) void k_head(const float* __restrict__ X,
                                              const float* __restrict__ A,
                                              const float* __restrict__ W,
                                              const float* __restrict__ avec,
                                              float* __restrict__ cH,
                                              float* __restrict__ g) {
    const int blk = blockIdx.x;
    const int b = blk >> 4, mq = blk & 15;
    const int t = threadIdx.x;
    __shared__ float sa[2 * OUTF];
    __shared__ float swa0[INF_], swa1[INF_];
    __shared__ float sh0[NN], sh1[NN];
    __shared__ float sd[256], ss0[256], ss1[256];
    __shared__ float se0[32], se1[32];

    sa[t] = avec[t];
    __syncthreads();
    // wa: thread t handles W row t (128 contiguous floats, float4)
    {
        const float4* Wr = (const float4*)(W + (size_t)t * OUTF);
        float w0 = 0.f, w1 = 0.f;
#pragma unroll 8
        for (int i = 0; i < 32; ++i) {
            float4 wv = Wr[i];
            w0 += wv.x * sa[4*i]     + wv.y * sa[4*i+1]
                + wv.z * sa[4*i+2]   + wv.w * sa[4*i+3];
            w1 += wv.x * sa[128+4*i]   + wv.y * sa[128+4*i+1]
                + wv.z * sa[128+4*i+2] + wv.w * sa[128+4*i+3];
        }
        swa0[t] = w0; swa1[t] = w1;
    }
    __syncthreads();
    // h0/h1: thread t handles X row (b, t) (256 floats, float4)
    {
        const float4* Xr = (const float4*)(X + (size_t)(b * NN + t) * INF_);
        float h0v = 0.f, h1v = 0.f;
#pragma unroll 8
        for (int i = 0; i < 64; ++i) {
            float4 xv = Xr[i];
            h0v += xv.x * swa0[4*i]   + xv.y * swa0[4*i+1]
                 + xv.z * swa0[4*i+2] + xv.w * swa0[4*i+3];
            h1v += xv.x * swa1[4*i]   + xv.y * swa1[4*i+1]
                 + xv.z * swa1[4*i+2] + xv.w * swa1[4*i+3];
        }
        sh0[t] = h0v; sh1[t] = h1v;
        if (mq == 0) {
            float hA = h0v + h1v;
            cH[b * NN + t] = hA > 0.f ? hA : 0.01f * hA;   // leaky 0.01
        }
    }
    __syncthreads();
    // em for columns m = 32*mq + (t&31); n-reduction split 8-way
    {
        const int m_l = t & 31, n_l = t >> 5;
        const float* Ap = A + (size_t)b * NN * MM + mq * 32 + m_l;
        float d = 0.f, s0 = 0.f, s1 = 0.f;
#pragma unroll 8
        for (int i = 0; i < 32; ++i) {
            int n = n_l * 32 + i;
            float av = Ap[n * MM];          // coalesced across m_l
            d += av;
            s0 += av * sh0[n];
            s1 += av * sh1[n];
        }
        sd[t] = d; ss0[t] = s0; ss1[t] = s1;
        __syncthreads();
        if (t < 32) {
            float D = 0.f, S0 = 0.f, S1 = 0.f;
#pragma unroll
            for (int j = 0; j < 8; ++j) {
                D  += sd[j * 32 + t];
                S0 += ss0[j * 32 + t];
                S1 += ss1[j * 32 + t];
            }
            if (D == 0.f) D = 1.f;
            se0[t] = S0 / D;                // em0[32mq+t]
            se1[t] = S1 / D;                // em1[32mq+t]
        }
        __syncthreads();
        // g[16mq+u] = g[256+16mq+u] = exp(leaky(em0[32mq+2u] + em1[32mq+2u+1]))
        if (t < 16) {
            float v = se0[2 * t] + se1[2 * t + 1];
            v = v > 0.f ? v : 0.01f * v;
            float gv = expf(v);
            g[b * MM + 16 * mq + t] = gv;
            g[b * MM + 256 + 16 * mq + t] = gv;
        }
    }
}

// K2 "mid": 640 blocks. Blocks 0..511: H = X@W row (split-K).
// Blocks 512..639: softmax row stats, 4 rows/block (one per wave).
//   low rows (n<128): exact per-row 2-value softmax weights w0,w1.
//   high rows: zero-shift softmax: rs0 = 1 / sum_m A*g[m].
__global__ __launch_bounds__(256) void k_mid(const float* __restrict__ X,
                                             const float* __restrict__ A,
                                             const float* __restrict__ W,
                                             const float* __restrict__ cH,
                                             const float* __restrict__ g,
                                             float* __restrict__ H,
                                             float* __restrict__ rs0,
                                             float* __restrict__ rs1) {
    const int blk = blockIdx.x;
    const int t = threadIdx.x;
    if (blk < 512) {
        __shared__ float xs[INF_];
        __shared__ float accs[256];
        const int bn = blk, f = t & 127, kh = t >> 7;
        xs[t] = X[bn * INF_ + t];
        __syncthreads();
        float acc = 0.f;
        const float* Wp = W + kh * 128 * OUTF + f;
        const float* xp = xs + kh * 128;
#pragma unroll 8
        for (int k = 0; k < 128; ++k) acc += xp[k] * Wp[k * OUTF];
        accs[t] = acc;
        __syncthreads();
        if (t < 128) H[bn * OUTF + t] = accs[t] + accs[t + 128];
    } else {
        const int sb = blk - 512;           // 0..127
        const int wv = t >> 6, lane = t & 63;
        const int bn = sb * 4 + wv;         // 0..511
        const int b = bn >> 8, n = bn & 255;
        const bool low = ((sb * 4) & 255) < 128;   // uniform per block
        __shared__ float sg[MM];
        if (!low) {
            sg[t] = g[b * MM + t];
            sg[t + 256] = g[b * MM + t + 256];
        }
        __syncthreads();
        const float* Ar = A + (size_t)bn * MM;
        if (low) {
            float c0 = 0.f, c1 = 0.f;
#pragma unroll
            for (int i = 0; i < 8; ++i) {
                float av = Ar[lane + 64 * i];
                if (i < 4) c0 += av; else c1 += av;
            }
#pragma unroll
            for (int off = 32; off >= 1; off >>= 1) {
                c0 += __shfl_xor(c0, off);
                c1 += __shfl_xor(c1, off);
            }
            if (lane == 0) {
                float ch0 = cH[b * NN + 2 * n];
                float ch1 = cH[b * NN + 2 * n + 1];
                float mx = fmaxf(c0 > 0.f ? ch0 : -INFINITY,
                                 c1 > 0.f ? ch1 : -INFINITY);
                float e0 = c0 > 0.f ? expf(ch0 - mx) : 0.f;
                float e1 = c1 > 0.f ? expf(ch1 - mx) : 0.f;
                float inv = 1.f / (c0 * e0 + c1 * e1);
                rs0[bn] = e0 * inv;
                rs1[bn] = e1 * inv;
            }
        } else {
            float s = 0.f;
#pragma unroll
            for (int i = 0; i < 8; ++i) {
                int m = lane + 64 * i;
                s += Ar[m] * sg[m];         // A in {0,1}: multiply = mask
            }
#pragma unroll
            for (int off = 32; off >= 1; off >>= 1) s += __shfl_xor(s, off);
            if (lane == 0) {
                rs0[bn] = 1.f / s;
                rs1[bn] = 0.f;
            }
        }
    }
}

// K3 "out": out[b,m,f] = sum_{n<128} A*w*H + g[m] * sum_{n>=128} A*rs0*H.
// 512 blocks x 256 thr (R5-P4 structure, eE = g[m] direct load).
__global__ __launch_bounds__(256) void k_out(const float* __restrict__ A,
                                             const float* __restrict__ H,
                                             const float* __restrict__ g,
                                             const float* __restrict__ rs0,
                                             const float* __restrict__ rs1,
                                             float* __restrict__ out) {
    __shared__ float sW[NN], sA0[NN], sA1[NN];
    __shared__ float2 sacc[2][128];
    const int blk = blockIdx.x;
    const int b = blk >> 8, mp = blk & 255;
    const int t = threadIdx.x;
    const int m0 = 2 * mp, m1 = 2 * mp + 1;
    const float* rsSel = (mp < 128) ? rs0 : rs1;   // w-half for low rows
    sW[t] = (t < 128) ? rsSel[b * NN + t] : rs0[b * NN + t];
    sA0[t] = A[((size_t)(b * NN + t)) * MM + m0];
    sA1[t] = A[((size_t)(b * NN + t)) * MM + m1];
    __syncthreads();
    const int f2 = t & 63;
    const int nh = (t >> 6) & 1;
    const int mh = t >> 7;
    const float* sA = mh ? sA1 : sA0;
    const float2* H2 = (const float2*)H + (size_t)b * NN * 64 + f2;
    float2 acc = {0.f, 0.f};
#pragma unroll 8
    for (int i = 0; i < 128; ++i) {
        int n = nh * 128 + i;
        float c = sA[n] * sW[n];            // LDS broadcasts
        float2 hv = H2[n * 64];             // coalesced 8B/lane
        acc.x = fmaf(c, hv.x, acc.x);
        acc.y = fmaf(c, hv.y, acc.y);
    }
    sacc[nh][mh * 64 + f2] = acc;
    __syncthreads();
    if (t < 128) {
        int mh2 = t >> 6, f2b = t & 63;
        int m = mp * 2 + mh2;
        float eE = g[b * MM + m];           // = exp(eLow[m])
        float2 lo = sacc[0][t];
        float2 hi = sacc[1][t];
        float2 r;
        r.x = lo.x + eE * hi.x;
        r.y = lo.y + eE * hi.y;
        ((float2*)out)[((size_t)b * MM + m) * 64 + f2b] = r;
    }
}

extern "C" void kernel_launch(void* const* d_in, const int* in_sizes, int n_in,
                              void* d_out, int out_size, void* d_ws, size_t ws_size,
                              hipStream_t stream) {
    const float* X = (const float*)d_in[0];
    const float* A = (const float*)d_in[1];
    const float* W = (const float*)d_in[2];
    const float* a = (const float*)d_in[3];
    float* out = (float*)d_out;
    float* ws = (float*)d_ws;

    float* H   = ws;            // B*N*OUTF = 65536
    float* cH  = ws + 65536;    // 512
    float* g   = ws + 66048;    // B*M = 1024
    float* rs0 = ws + 67072;    // B*N = 512
    float* rs1 = ws + 67584;    // B*N = 512

    k_head<<<32, 256, 0, stream>>>(X, A, W, a, cH, g);
    k_mid<<<640, 256, 0, stream>>>(X, A, W, cH, g, H, rs0, rs1);
    k_out<<<512, 256, 0, stream>>>(A, H, g, rs0, rs1, out);
}

// Round 7
// 26.592 us; speedup vs baseline: 7.2645x; 1.2221x over previous
//
#include <hip/hip_runtime.h>

#define BB 2
#define NN 256
#define MM 512
#define INF_ 256
#define OUTF 128

// N1: per (b,n) row: H = X@W (split-K over 2 thread-halves), h0 = H.a0,
// h1 = H.a1, cH = leaky(h0+h1). Rows n>=128 also zero S[b,n-128].
__global__ __launch_bounds__(256) void k_gemm(const float* __restrict__ X,
                                              const float* __restrict__ W,
                                              const float* __restrict__ avec,
                                              float* __restrict__ H,
                                              float* __restrict__ h0,
                                              float* __restrict__ h1,
                                              float* __restrict__ cH,
                                              float* __restrict__ S) {
    int bn = blockIdx.x;      // b*N + n
    int t = threadIdx.x;
    int f = t & 127, kh = t >> 7;
    __shared__ float xs[INF_];
    xs[t] = X[bn * INF_ + t];
    __syncthreads();
    float acc = 0.f;
    const float* Wp = W + kh * 128 * OUTF + f;
    const float* xp = xs + kh * 128;
#pragma unroll 8
    for (int k = 0; k < 128; ++k) acc += xp[k] * Wp[k * OUTF];
    __shared__ float accs[256];
    accs[t] = acc;
    __syncthreads();
    float a2 = 0.f, p0 = 0.f, p1 = 0.f;
    if (t < 128) {
        a2 = accs[t] + accs[t + 128];
        H[bn * OUTF + t] = a2;
        p0 = a2 * avec[t];
        p1 = a2 * avec[OUTF + t];
    }
#pragma unroll
    for (int off = 32; off >= 1; off >>= 1) {
        p0 += __shfl_down(p0, off);
        p1 += __shfl_down(p1, off);
    }
    __shared__ float r0[4], r1[4];
    int wv = t >> 6, ln = t & 63;
    if (ln == 0) { r0[wv] = p0; r1[wv] = p1; }
    __syncthreads();
    if (t == 0) {
        float s0 = r0[0] + r0[1] + r0[2] + r0[3];
        float s1 = r1[0] + r1[1] + r1[2] + r1[3];
        h0[bn] = s0;
        h1[bn] = s1;
        float hA = s0 + s1;
        cH[bn] = hA > 0.f ? hA : 0.01f * hA;   // leaky_relu 0.01
        int n = bn & 255;
        if (n >= 128) S[(bn >> 8) * 128 + n - 128] = 0.f;
    }
}

// N2: 96 blocks.
// Blocks 0..31 (b = blk>>4, mq = blk&15): em0/em1 for cols [32mq,32mq+32),
//   g for slots 16mq..16mq+15 (dup at +256), then atomicAdd partial
//   S[b,n] += sum_u g[u]*(A[n,16mq+u]+A[n,256+16mq+u]) for n in [128,256).
// Blocks 32..95: low-row (n<128) softmax stats: exact 2-value weights from
//   cH + A half-row counts. 4 rows/block (one per wave).
__global__ __launch_bounds__(256) void k_emg(const float* __restrict__ A,
                                             const float* __restrict__ h0,
                                             const float* __restrict__ h1,
                                             const float* __restrict__ cH,
                                             float* __restrict__ g,
                                             float* __restrict__ rs0,
                                             float* __restrict__ rs1,
                                             float* __restrict__ S) {
    const int blk = blockIdx.x;
    const int t = threadIdx.x;
    if (blk < 32) {
        const int b = blk >> 4, mq = blk & 15;
        const int m_l = t & 31, n_l = t >> 5;
        __shared__ float sh0[NN], sh1[NN];
        __shared__ float sd[256], ss0[256], ss1[256];
        __shared__ float se0[32], se1[32], sg[16];
        sh0[t] = h0[b * NN + t];
        sh1[t] = h1[b * NN + t];
        __syncthreads();
        const float* Ap = A + (size_t)b * NN * MM + mq * 32 + m_l;
        float d = 0.f, s0 = 0.f, s1 = 0.f;
#pragma unroll 8
        for (int i = 0; i < 32; ++i) {
            int n = n_l * 32 + i;
            float av = Ap[n * MM];          // coalesced across m_l
            d += av;
            s0 += av * sh0[n];
            s1 += av * sh1[n];
        }
        sd[t] = d; ss0[t] = s0; ss1[t] = s1;
        __syncthreads();
        if (t < 32) {
            float D = 0.f, S0 = 0.f, S1 = 0.f;
#pragma unroll
            for (int j = 0; j < 8; ++j) {
                D  += sd[j * 32 + t];
                S0 += ss0[j * 32 + t];
                S1 += ss1[j * 32 + t];
            }
            if (D == 0.f) D = 1.f;
            se0[t] = S0 / D;                // em0[32mq+t]
            se1[t] = S1 / D;                // em1[32mq+t]
        }
        __syncthreads();
        if (t < 16) {
            // g[16mq+u] = exp(leaky(em0[32mq+2u] + em1[32mq+2u+1]))
            float v = se0[2 * t] + se1[2 * t + 1];
            v = v > 0.f ? v : 0.01f * v;
            float gv = expf(v);
            g[b * MM + 16 * mq + t] = gv;
            g[b * MM + 256 + 16 * mq + t] = gv;
            sg[t] = gv;
        }
        __syncthreads();
        // S partials for high rows, using local g only (order-independent)
        {
            const int u = t & 15, ng = t >> 4;   // 16 col-lanes x 16 n-groups
            const float gv = sg[u];
            const float* Alo = A + (size_t)b * NN * MM + 16 * mq + u;
#pragma unroll
            for (int step = 0; step < 8; ++step) {
                int n = 128 + ng + 16 * step;
                const float* Ar = Alo + (size_t)n * MM;
                float val = gv * (Ar[0] + Ar[256]);
                val += __shfl_xor(val, 1);
                val += __shfl_xor(val, 2);
                val += __shfl_xor(val, 4);
                val += __shfl_xor(val, 8);
                if (u == 0) atomicAdd(&S[b * 128 + n - 128], val);
            }
        }
    } else {
        // low-row stats: l = (blk-32)*4 + wave -> b = l>>7, n = l&127
        const int wv = t >> 6, lane = t & 63;
        const int l = (blk - 32) * 4 + wv;
        const int b = l >> 7, n = l & 127;
        const int bn = b * NN + n;
        const float* Ar = A + (size_t)bn * MM;
        float c0 = 0.f, c1 = 0.f;
#pragma unroll
        for (int i = 0; i < 8; ++i) {
            float av = Ar[lane + 64 * i];
            if (i < 4) c0 += av; else c1 += av;
        }
#pragma unroll
        for (int off = 32; off >= 1; off >>= 1) {
            c0 += __shfl_xor(c0, off);
            c1 += __shfl_xor(c1, off);
        }
        if (lane == 0) {
            float ch0 = cH[b * NN + 2 * n];
            float ch1 = cH[b * NN + 2 * n + 1];
            float mx = fmaxf(c0 > 0.f ? ch0 : -INFINITY,
                             c1 > 0.f ? ch1 : -INFINITY);
            float e0 = c0 > 0.f ? expf(ch0 - mx) : 0.f;
            float e1 = c1 > 0.f ? expf(ch1 - mx) : 0.f;
            float inv = 1.f / (c0 * e0 + c1 * e1);
            rs0[bn] = e0 * inv;
            rs1[bn] = e1 * inv;
        }
    }
}

// N3: out[b,m,f] = sum_{n<128} A*w*H + g[m] * sum_{n>=128} A*(1/S_n)*H.
// 512 blocks x 256 thr: block = (b, m-pair mp).
__global__ __launch_bounds__(256) void k_out(const float* __restrict__ A,
                                             const float* __restrict__ H,
                                             const float* __restrict__ g,
                                             const float* __restrict__ rs0,
                                             const float* __restrict__ rs1,
                                             const float* __restrict__ S,
                                             float* __restrict__ out) {
    __shared__ float sW[NN], sA0[NN], sA1[NN];
    __shared__ float2 sacc[2][128];
    const int blk = blockIdx.x;
    const int b = blk >> 8, mp = blk & 255;
    const int t = threadIdx.x;
    const int m0 = 2 * mp, m1 = 2 * mp + 1;
    if (t < 128) {
        sW[t] = ((mp < 128) ? rs0 : rs1)[b * NN + t];   // low-row weight half
    } else {
        sW[t] = 1.f / S[b * 128 + (t - 128)];           // high-row 1/S_n
    }
    sA0[t] = A[((size_t)(b * NN + t)) * MM + m0];
    sA1[t] = A[((size_t)(b * NN + t)) * MM + m1];
    __syncthreads();
    const int f2 = t & 63;
    const int nh = (t >> 6) & 1;
    const int mh = t >> 7;
    const float* sA = mh ? sA1 : sA0;
    const float2* H2 = (const float2*)H + (size_t)b * NN * 64 + f2;
    float2 acc = {0.f, 0.f};
#pragma unroll 8
    for (int i = 0; i < 128; ++i) {
        int n = nh * 128 + i;
        float c = sA[n] * sW[n];            // LDS broadcasts
        float2 hv = H2[n * 64];             // coalesced 8B/lane
        acc.x = fmaf(c, hv.x, acc.x);
        acc.y = fmaf(c, hv.y, acc.y);
    }
    sacc[nh][mh * 64 + f2] = acc;
    __syncthreads();
    if (t < 128) {
        int mh2 = t >> 6, f2b = t & 63;
        int m = mp * 2 + mh2;
        float eE = g[b * MM + m];           // = exp(eLow[m])
        float2 lo = sacc[0][t];
        float2 hi = sacc[1][t];
        float2 r;
        r.x = lo.x + eE * hi.x;
        r.y = lo.y + eE * hi.y;
        ((float2*)out)[((size_t)b * MM + m) * 64 + f2b] = r;
    }
}

extern "C" void kernel_launch(void* const* d_in, const int* in_sizes, int n_in,
                              void* d_out, int out_size, void* d_ws, size_t ws_size,
                              hipStream_t stream) {
    const float* X = (const float*)d_in[0];
    const float* A = (const float*)d_in[1];
    const float* W = (const float*)d_in[2];
    const float* a = (const float*)d_in[3];
    float* out = (float*)d_out;
    float* ws = (float*)d_ws;

    float* H   = ws;            // B*N*OUTF = 65536
    float* h0  = ws + 65536;    // 512
    float* h1  = ws + 66048;    // 512
    float* cH  = ws + 66560;    // 512
    float* g   = ws + 67072;    // B*M = 1024
    float* rs0 = ws + 68096;    // B*N = 512 (low halves used)
    float* rs1 = ws + 68608;    // B*N = 512 (low halves used)
    float* S   = ws + 69120;    // B*128 = 256 (high-row softmax denominators)

    k_gemm<<<BB * NN, 256, 0, stream>>>(X, W, a, H, h0, h1, cH, S);
    k_emg<<<96, 256, 0, stream>>>(A, h0, h1, cH, g, rs0, rs1, S);
    k_out<<<512, 256, 0, stream>>>(A, H, g, rs0, rs1, S, out);
}